// Round 4
// baseline (2415.463 us; speedup 1.0000x reference)
//
#include <hip/hip_runtime.h>
#include <hip/hip_fp16.h>

#define T_DIM 1024
#define B_DIM 64
#define F_DIM 512
#define H_DIM 512
#define G4    2048
#define HSZ   (B_DIM*H_DIM)   // 32768

typedef _Float16 h16;
typedef unsigned long long u64;
typedef _Float16 v8h __attribute__((ext_vector_type(8)));
typedef _Float16 v4h __attribute__((ext_vector_type(4)));
typedef _Float16 v2h __attribute__((ext_vector_type(2)));
typedef float    v4f __attribute__((ext_vector_type(4)));
typedef unsigned v4u __attribute__((ext_vector_type(4)));
typedef unsigned v2u __attribute__((ext_vector_type(2)));

// scan decomposition: 8 row-groups x 8 rows, 16 WGs per group (grid 128).
// Teams formed by XCD census; h exchange via that XCD's L2.
// Two-stage protocol: tag-free u32 payload (8KB/group/phase) + per-WAVE
// 4B flags (flag = t+1, stored after a vmcnt(0) store-ack fence). Failed
// poll rounds read 256B (flag lines) instead of 16KB -> no L2 poll storm.
#define NGRP   8
#define GROWS  8
#define NWG    128
#define WSTEPS 16              // xp staging window
// hbuf layout: u32 pay[2][NGRP][2048] | u32 flags[NGRP][64] | u64 ctrl
#define FLAG32_OFF 32768                      // u32 index
#define DESC_OFF  ((size_t)16640)             // u64 index (after pay+flags)
#define TRIAL_OFF (DESC_OFF + NWG)
#define VOTE_OFF  (TRIAL_OFF + NWG)
#define ABORT_OFF (VOTE_OFF + NWG)

#define XP_HALVES ((size_t)T_DIM * 256 * 2 * 64 * 4)
#define XP_BYTES  (XP_HALVES * 2)
#define HB_WORDS  (ABORT_OFF + NGRP)
#define HB_BYTES  (HB_WORDS * 8)
#define X16_BYTES ((size_t)B_DIM * T_DIM * F_DIM * 2)   // 64 MB
#define WXP_BYTES ((size_t)G4 * F_DIM * 2)              // 2 MB

// ---------------------------------------------------------------------------
// Phase 0a: X fp32 -> fp16, straight copy (bandwidth-bound).
// ---------------------------------------------------------------------------
__global__ __launch_bounds__(256) void conv_x_kernel(
    const float* __restrict__ X, h16* __restrict__ X16)
{
  const size_t total4 = (size_t)B_DIM * T_DIM * F_DIM / 4;   // 8388608
  for (size_t i = blockIdx.x * 256 + threadIdx.x; i < total4;
       i += (size_t)gridDim.x * 256) {
    float4 v = ((const float4*)X)[i];
    v4h w = { (h16)v.x, (h16)v.y, (h16)v.z, (h16)v.w };
    ((v4h*)X16)[i] = w;
  }
}

// ---------------------------------------------------------------------------
// Phase 0b: Wx fp32 -> Wxp[pc][k] fp16, pre-permuted into staging order.
// ---------------------------------------------------------------------------
__global__ __launch_bounds__(256) void conv_w_kernel(
    const float* __restrict__ Wx, h16* __restrict__ Wxp)
{
  const int gid = blockIdx.x * 256 + threadIdx.x;   // 512 blocks -> 131072
  const int pcg = gid >> 6;                         // 0..2047
  const int k8  = gid & 63;                         // 0..63 (8 k's each)
  const int ub  = pcg >> 5, Tt = (pcg >> 4) & 1, nn = pcg & 15;
  const int gcol = (Tt*2 + (nn >> 3))*512 + ub*8 + (nn & 7);
  v8h w;
  #pragma unroll
  for (int j = 0; j < 8; ++j)
    w[j] = (h16)Wx[(size_t)(k8*8 + j)*G4 + gcol];
  *(v8h*)(Wxp + (size_t)pcg*512 + k8*8) = w;
}

// ---------------------------------------------------------------------------
// Phase 1: x_proj = X16 @ Wxp + b -> fp16 MFMA C/D fragment layout (unchanged).
// ---------------------------------------------------------------------------
__global__ __launch_bounds__(256) void xproj_kernel(
    const h16* __restrict__ X16, const h16* __restrict__ Wxp,
    const float* __restrict__ bias, h16* __restrict__ xp)
{
  __shared__ __align__(16) h16 As[128*72];
  __shared__ __align__(16) h16 Bs[128*72];
  const int wgid = blockIdx.x;               // 8192 blocks
  const int wgn  = wgid & 15;
  const int bg   = (wgid >> 4) & 3;
  const int t0   = (wgid >> 6) * 8;
  const int tid  = threadIdx.x;
  const int lane = tid & 63;
  const int wv   = tid >> 6;
  const int mh   = wv & 1, nh = wv >> 1;
  const int n    = lane & 15, quad = lane >> 4;

  v4f acc[4][4];
  #pragma unroll
  for (int mi = 0; mi < 4; ++mi)
    #pragma unroll
    for (int ni = 0; ni < 4; ++ni) acc[mi][ni] = {0.f, 0.f, 0.f, 0.f};

  const int m  = tid >> 1;
  const int kh = tid & 1;
  const int abl = m & 15, atl = m >> 4;
  const h16* asrc0 = X16 + ((size_t)(bg*16 + abl)*T_DIM + (t0 + atl))*F_DIM
                         + kh*32;
  const h16* bsrc0 = Wxp + (size_t)(wgn*128 + m)*512 + kh*32;
  h16* adst = As + m*72 + kh*32;
  h16* bdst = Bs + m*72 + kh*32;

  for (int kc = 0; kc < 8; ++kc) {
    __syncthreads();
    {
      const h16* asrc = asrc0 + kc*64;
      const h16* bsrc = bsrc0 + kc*64;
      #pragma unroll
      for (int j = 0; j < 32; j += 8) {
        *(v8h*)(adst + j) = *(const v8h*)(asrc + j);
        *(v8h*)(bdst + j) = *(const v8h*)(bsrc + j);
      }
    }
    __syncthreads();
    #pragma unroll
    for (int kk = 0; kk < 2; ++kk) {
      v8h aF[4], bF[4];
      #pragma unroll
      for (int mi = 0; mi < 4; ++mi)
        aF[mi] = *(const v8h*)(As + ((mh*4 + mi)*16 + n)*72 + kk*32 + quad*8);
      #pragma unroll
      for (int ni = 0; ni < 4; ++ni)
        bF[ni] = *(const v8h*)(Bs + ((nh*4 + ni)*16 + n)*72 + kk*32 + quad*8);
      #pragma unroll
      for (int mi = 0; mi < 4; ++mi)
        #pragma unroll
        for (int ni = 0; ni < 4; ++ni)
          acc[mi][ni] = __builtin_amdgcn_mfma_f32_16x16x32_f16(
              aF[mi], bF[ni], acc[mi][ni], 0, 0, 0);
    }
  }
  #pragma unroll
  for (int ni = 0; ni < 4; ++ni) {
    int pc0  = wgn*128 + (nh*4 + ni)*16;
    int ub   = pc0 >> 5, Tt = (pc0 >> 4) & 1;
    int gcol = (Tt*2 + (n >> 3))*512 + ub*8 + (n & 7);
    float bv = bias[gcol];
    int wg2  = bg*64 + ub;
    #pragma unroll
    for (int mi = 0; mi < 4; ++mi) {
      int t = t0 + mh*4 + mi;
      size_t off = ((((size_t)t*256 + wg2)*2 + Tt)*256) + lane*4;
      v4h o = { (h16)(acc[mi][ni][0] + bv), (h16)(acc[mi][ni][1] + bv),
                (h16)(acc[mi][ni][2] + bv), (h16)(acc[mi][ni][3] + bv) };
      *(v4h*)(xp + off) = o;
    }
  }
}

// ---------------------------------------------------------------------------
// Phase 2: persistent scan; flag-gated exchange through the XCD L2.
// ---------------------------------------------------------------------------
__device__ __forceinline__ float fsig(float x) {
  return __builtin_amdgcn_rcpf(1.f + __expf(-x));
}
__device__ __forceinline__ float ftanh(float x) {
  return 1.f - 2.f * __builtin_amdgcn_rcpf(__expf(2.f*x) + 1.f);
}

// nt load: no L1 allocation; served by XCD L2 when the line is there.
__device__ __forceinline__ u64 load_nt_u64(const u64* p) {
  v2u r;
  asm volatile("global_load_dwordx2 %0, %1, off nt\n\ts_waitcnt vmcnt(0)"
               : "=v"(r) : "v"(p) : "memory");
  return ((u64)r.y << 32) | (u64)r.x;
}

__global__ __launch_bounds__(256, 1) void scan_kernel(
    const float* __restrict__ Wh, const h16* __restrict__ xp,
    u64* __restrict__ hbuf, float* __restrict__ out)
{
  const int bx   = blockIdx.x;          // 0..127
  const int tid  = threadIdx.x;         // 0..255
  const int wv   = tid >> 6;
  const int lane = tid & 63;
  const int n    = lane & 15, quad = lane >> 4;

  __shared__ __align__(16) unsigned hlds[2][2052];  // 2048 payloads + zero pad
  __shared__ __align__(16) unsigned char xs[4*8192];// xp window: 4 wv x 16 slot x 512B
  __shared__ float gbuf[4][16*33];                  // per-wave gate exchange
  __shared__ unsigned char xcds[NWG];
  __shared__ unsigned char pos2bx[NWG];
  __shared__ int sflag[2];

  unsigned* const pay = (unsigned*)hbuf;            // u32 payload view
  unsigned* const flg = pay + FLAG32_OFF;           // u32 flags view

  // ---- census: read physical XCD, publish, gather ----
  unsigned xcd;
  asm volatile("s_getreg_b32 %0, hwreg(20, 0, 32)" : "=s"(xcd)); // XCC_ID
  xcd &= 7u;
  u64* const desc = hbuf + DESC_OFF;
  if (tid == 0)
    __hip_atomic_store(desc + bx, ((u64)0xABu << 56) | (u64)xcd,
                       __ATOMIC_RELAXED, __HIP_MEMORY_SCOPE_AGENT);
  if (tid < NWG) {
    u64 d = __hip_atomic_load(desc + tid, __ATOMIC_RELAXED,
                              __HIP_MEMORY_SCOPE_AGENT);
    while ((unsigned)(d >> 56) != 0xABu) {
      __builtin_amdgcn_s_sleep(1);
      d = __hip_atomic_load(desc + tid, __ATOMIC_RELAXED,
                            __HIP_MEMORY_SCOPE_AGENT);
    }
    xcds[tid] = (unsigned char)(d & 7u);
  }
  if (tid < 4) { hlds[0][2048 + tid] = 0; hlds[1][2048 + tid] = 0; }
  __syncthreads();

  // deterministic team assignment by (xcd, bx) sort
  int start = 0, cnt = 0, rank = 0;
  for (int i = 0; i < NWG; ++i) {
    const int x = xcds[i];
    start += (x < (int)xcd) ? 1 : 0;
    cnt   += (x == (int)xcd) ? 1 : 0;
    rank  += (x == (int)xcd && i < bx) ? 1 : 0;
  }
  const int pos = start + rank;
  const int g = pos >> 4, w = pos & 15;     // group 0..7, slot 0..15
  bool fast = (g*16 >= start) && (g*16 + 16 <= start + cnt);

  // ---- trial handshake: plain-store -> nt-load visibility on this exact
  // placement; bounded wait, then agent-scope unanimous vote. ----
  if (fast) {
    if (tid < NWG) {
      const int xi = xcds[tid];
      int st = 0, rk = 0;
      for (int i = 0; i < NWG; ++i) {
        const int x = xcds[i];
        st += (x < xi) ? 1 : 0;
        rk += (x == xi && i < tid) ? 1 : 0;
      }
      pos2bx[st + rk] = (unsigned char)tid;
    }
    __syncthreads();
    u64* const trial = hbuf + TRIAL_OFF;
    u64* const vote  = hbuf + VOTE_OFF;
    if (tid == 0)
      __hip_atomic_store(trial + bx, ((u64)0xCDu << 56) | (u64)bx,
                         __ATOMIC_RELAXED, __HIP_MEMORY_SCOPE_WORKGROUP);
    int seen = 1;
    if (tid < 16) {
      const int tb = pos2bx[g*16 + tid];
      const u64 want = ((u64)0xCDu << 56) | (u64)tb;
      seen = 0;
      for (int it = 0; it < 1024; ++it) {
        if (load_nt_u64(trial + tb) == want) { seen = 1; break; }
        __builtin_amdgcn_s_sleep(1);
      }
    }
    if (tid < 64) {
      const int okw = __all(seen);
      if (tid == 0) sflag[0] = okw;
    }
    __syncthreads();
    if (tid == 0)
      __hip_atomic_store(vote + bx, ((u64)0xEFu << 56) | (u64)(sflag[0] & 1),
                         __ATOMIC_RELAXED, __HIP_MEMORY_SCOPE_AGENT);
    int vok = 1;
    if (tid < 16) {
      const int tb = pos2bx[g*16 + tid];
      u64 d = __hip_atomic_load(vote + tb, __ATOMIC_RELAXED,
                                __HIP_MEMORY_SCOPE_AGENT);
      while ((unsigned)(d >> 56) != 0xEFu) {
        __builtin_amdgcn_s_sleep(1);
        d = __hip_atomic_load(vote + tb, __ATOMIC_RELAXED,
                              __HIP_MEMORY_SCOPE_AGENT);
      }
      vok = (int)(d & 1);
    }
    if (tid < 64) {
      const int allv = __all(vok);
      if (tid == 0) sflag[1] = allv;
    }
    __syncthreads();
    fast = (sflag[1] != 0);
  }
  const bool everfast = fast;

  const int ub  = w*4 + wv;           // unit-block 0..63 (8 units)
  const int u0  = ub*8;
  const int g01 = n >> 3;
  const int uc  = u0 + (n & 7);

  // persistent B fragments: tile0 = gates {i,f}, tile1 = {g,o}
  v8h bF0[16], bF1[16];
  #pragma unroll
  for (int kk = 0; kk < 16; ++kk) {
    const int kb = kk*32 + quad*8;
    v8h f0, f1;
    #pragma unroll
    for (int j = 0; j < 8; ++j) {
      f0[j] = (h16)Wh[(size_t)(kb + j)*G4 + (g01*512 + uc)];
      f1[j] = (h16)Wh[(size_t)(kb + j)*G4 + ((2 + g01)*512 + uc)];
    }
    bF0[kk] = f0; bF1[kk] = f1;
  }

  float c0 = 0.f, c1 = 0.f, hf0 = 0.f, hf1 = 0.f;

  const bool act = (n < GROWS);              // h-owner lane (row n, 2 units)
  const int  pW  = ub*32 + n*4 + quad;       // producer u32 index
  unsigned* const pay0b = pay + (size_t)g*2048;          // phase 0
  unsigned* const pay1b = pay + (size_t)(NGRP + g)*2048; // phase 1
  u64* const abw  = hbuf + ABORT_OFF + g;
  const unsigned* const flagp = flg + g*64 + lane;       // poll addr (per lane)
  unsigned* const flagw = flg + g*64 + ub;               // publish addr (wave)
  unsigned lw0 = 0, lw1 = 0, lfv = 0;        // last published values (abort)

  // xp addressing: group g rows = old 16-row group (g>>1), parity gp = g&1.
  const int bgrp = g >> 1;
  const int gp   = g & 1;
  unsigned char* const xsw = xs + wv*8192;   // this wave's window block

  // staging piece decomposition (8 x 16B per thread per window)
  int pslot[8], pchunk[8], pk[8];
  #pragma unroll
  for (int j = 0; j < 8; ++j) {
    const int p2 = j*64 + lane;              // 0..511
    pslot[j]  = p2 >> 5;
    pchunk[j] = (p2 >> 4) & 1;
    pk[j]     = p2 & 15;
  }
  v4u rg[8];
  #pragma unroll
  for (int j = 0; j < 8; ++j) {
    const size_t ubase = ((size_t)pslot[j]*256 + bgrp*64 + ub)*512;
    rg[j] = *(const v4u*)(xp + ubase + gp*128 + pchunk[j]*256 + pk[j]*8);
  }

  // A-fragment base in hlds; pad rows read the zero pad
  const int hbase = act ? (quad*32 + n*4) : 2048;
  const int hoff  = act ? 128 : 0;

  for (int t = 0; t < T_DIM; ++t) {
    const int p = t & 1;
    const int s = t & 15;
    const unsigned target = (unsigned)t;

    // ---- stage 1: flag poll (256B/group/round; wave-coalesced) ----
    if (fast) {
      int rounds = 0;
      for (;;) {
        unsigned fv;
        asm volatile("global_load_dword %0, %1, off nt\n\ts_waitcnt vmcnt(0)"
                     : "=v"(fv) : "v"(flagp) : "memory");
        if (__all((int)(fv >= target))) break;
        ++rounds;
        if ((rounds & 31) == 0) {
          u64 ab = __hip_atomic_load(abw, __ATOMIC_RELAXED,
                                     __HIP_MEMORY_SCOPE_AGENT);
          if (__any((int)(ab != 0)) || rounds > 1024) {
            // abort: re-publish last values at agent scope, go slow
            __hip_atomic_store(abw, (u64)1, __ATOMIC_RELAXED,
                               __HIP_MEMORY_SCOPE_AGENT);
            if (act) {
              __hip_atomic_store(pay0b + pW, lw0, __ATOMIC_RELAXED,
                                 __HIP_MEMORY_SCOPE_AGENT);
              __hip_atomic_store(pay1b + pW, lw1, __ATOMIC_RELAXED,
                                 __HIP_MEMORY_SCOPE_AGENT);
            }
            asm volatile("s_waitcnt vmcnt(0)" ::: "memory");
            if (lane == 0)
              __hip_atomic_store(flagw, lfv, __ATOMIC_RELAXED,
                                 __HIP_MEMORY_SCOPE_AGENT);
            fast = false;
            break;
          }
        }
        if (rounds > 8) __builtin_amdgcn_s_sleep(1);
      }
    }
    if (!fast) {
      int rounds = 0;
      for (;;) {
        unsigned fv = __hip_atomic_load(flagp, __ATOMIC_RELAXED,
                                        __HIP_MEMORY_SCOPE_AGENT);
        if (__all((int)(fv >= target))) break;
        ++rounds;
        if ((rounds & 63) == 0 && lane == 0)
          __hip_atomic_store(abw, (u64)1, __ATOMIC_RELAXED,
                             __HIP_MEMORY_SCOPE_AGENT);   // wake fast peers
        __builtin_amdgcn_s_sleep(1);
      }
    }

    // window boundary: commit pre-issued xp loads to LDS (drained by poll)
    if (s == 0) {
      #pragma unroll
      for (int j = 0; j < 8; ++j)
        *(v4u*)(xsw + pslot[j]*512 + pchunk[j]*256 + pk[j]*16) = rg[j];
    }

    // ---- stage 2: one-shot payload fetch (8KB/WG) ----
    v2u r0, r1, r2, r3;
    {
      const unsigned* pb = (p ? pay1b : pay0b) + tid*2;
      if (fast) {
        asm volatile("global_load_dwordx2 %0, %1, off nt"
                     : "=v"(r0) : "v"(pb) : "memory");
        asm volatile("global_load_dwordx2 %0, %1, off nt"
                     : "=v"(r1) : "v"(pb + 512) : "memory");
        asm volatile("global_load_dwordx2 %0, %1, off nt"
                     : "=v"(r2) : "v"(pb + 1024) : "memory");
        asm volatile("global_load_dwordx2 %0, %1, off nt"
                     : "=v"(r3) : "v"(pb + 1536) : "memory");
        asm volatile("s_waitcnt vmcnt(0)"
                     : "+v"(r0), "+v"(r1), "+v"(r2), "+v"(r3) :: "memory");
        __builtin_amdgcn_sched_barrier(0);
      } else {
        u64 w0 = __hip_atomic_load((const u64*)(pb),        __ATOMIC_RELAXED,
                                   __HIP_MEMORY_SCOPE_AGENT);
        u64 w1 = __hip_atomic_load((const u64*)(pb + 512),  __ATOMIC_RELAXED,
                                   __HIP_MEMORY_SCOPE_AGENT);
        u64 w2 = __hip_atomic_load((const u64*)(pb + 1024), __ATOMIC_RELAXED,
                                   __HIP_MEMORY_SCOPE_AGENT);
        u64 w3 = __hip_atomic_load((const u64*)(pb + 1536), __ATOMIC_RELAXED,
                                   __HIP_MEMORY_SCOPE_AGENT);
        r0 = (v2u){(unsigned)w0, (unsigned)(w0 >> 32)};
        r1 = (v2u){(unsigned)w1, (unsigned)(w1 >> 32)};
        r2 = (v2u){(unsigned)w2, (unsigned)(w2 >> 32)};
        r3 = (v2u){(unsigned)w3, (unsigned)(w3 >> 32)};
      }
    }

    // redistribute payload dwords into linear hlds (b64 writes)
    {
      v2u* hl = (v2u*)hlds[p];
      hl[tid]       = r0;
      hl[tid + 256] = r1;
      hl[tid + 512] = r2;
      hl[tid + 768] = r3;
    }
    __syncthreads();

    // per-step xp from LDS (2 x ds_read_b64)
    const unsigned char* xb = xsw + s*512 + (quad & 1)*128 + n*8;
    v4h x0 = *(const v4h*)xb;
    v4h x1 = *(const v4h*)(xb + 256);

    v4f acc0 = { (float)x0[0], (float)x0[1], (float)x0[2], (float)x0[3] };
    v4f acc1 = { (float)x1[0], (float)x1[1], (float)x1[2], (float)x1[3] };
    v4f acc2 = { 0.f, 0.f, 0.f, 0.f };
    v4f acc3 = { 0.f, 0.f, 0.f, 0.f };
    const unsigned* hfr = &hlds[p][hbase];
    #pragma unroll
    for (int kk = 0; kk < 8; ++kk) {
      v8h a0 = *(const v8h*)(hfr + kk*hoff);
      v8h a1 = *(const v8h*)(hfr + (kk+8)*hoff);
      acc0 = __builtin_amdgcn_mfma_f32_16x16x32_f16(a0, bF0[kk],   acc0, 0,0,0);
      acc1 = __builtin_amdgcn_mfma_f32_16x16x32_f16(a0, bF1[kk],   acc1, 0,0,0);
      acc2 = __builtin_amdgcn_mfma_f32_16x16x32_f16(a1, bF0[kk+8], acc2, 0,0,0);
      acc3 = __builtin_amdgcn_mfma_f32_16x16x32_f16(a1, bF1[kk+8], acc3, 0,0,0);
    }
    acc0 += acc2; acc1 += acc3;

    // gate exchange within wave
    float* gb = gbuf[wv];
    #pragma unroll
    for (int r = 0; r < 4; ++r) {
      const int row = quad*4 + r;
      gb[row*33 + n]      = acc0[r];
      gb[row*33 + 16 + n] = acc1[r];
    }
    __builtin_amdgcn_wave_barrier();
    const float* gr = gb + n*33;
    const int ua2 = quad*2;
    float gi0 = gr[ua2],   gf0 = gr[8+ua2], gg0 = gr[16+ua2], go0 = gr[24+ua2];
    float gi1 = gr[ua2+1], gf1 = gr[9+ua2], gg1 = gr[17+ua2], go1 = gr[25+ua2];
    __builtin_amdgcn_wave_barrier();

    gi0 = fsig(gi0); gf0 = fsig(gf0); gg0 = ftanh(gg0); go0 = fsig(go0);
    gi1 = fsig(gi1); gf1 = fsig(gf1); gg1 = ftanh(gg1); go1 = fsig(go1);
    c0 = gf0*c0 + gi0*gg0;  hf0 = go0*ftanh(c0);
    c1 = gf1*c1 + gi1*gg1;  hf1 = go1*ftanh(c1);

    // ---- publish: payload stores -> vmcnt(0) ack fence -> wave flag ----
    if (t < T_DIM - 1) {
      if (act) {
        union { v2h v; unsigned u; } pw_;
        pw_.v = (v2h){ (h16)hf0, (h16)hf1 };
        unsigned* pp = (p ? pay0b : pay1b) + pW;   // phase (t+1)&1
        if (fast)
          __hip_atomic_store(pp, pw_.u, __ATOMIC_RELAXED,
                             __HIP_MEMORY_SCOPE_WORKGROUP);
        else
          __hip_atomic_store(pp, pw_.u, __ATOMIC_RELAXED,
                             __HIP_MEMORY_SCOPE_AGENT);
        if (p) lw0 = pw_.u; else lw1 = pw_.u;
      }
      asm volatile("s_waitcnt vmcnt(0)" ::: "memory");
      lfv = (unsigned)(t + 1);
      if (lane == 0) {
        if (fast)
          __hip_atomic_store(flagw, lfv, __ATOMIC_RELAXED,
                             __HIP_MEMORY_SCOPE_WORKGROUP);
        else
          __hip_atomic_store(flagw, lfv, __ATOMIC_RELAXED,
                             __HIP_MEMORY_SCOPE_AGENT);
      }
    }

    // end of window: issue next window's xp loads (drained by next poll)
    if (s == WSTEPS - 1 && t + 1 < T_DIM) {
      const int tw = t + 1;
      #pragma unroll
      for (int j = 0; j < 8; ++j) {
        const size_t ubase = ((size_t)(tw + pslot[j])*256 + bgrp*64 + ub)*512;
        rg[j] = *(const v4u*)(xp + ubase + gp*128 + pchunk[j]*256 + pk[j]*8);
      }
    }
  }

  // close the mixed-mode exit window: ever-fast waves re-publish at agent
  // scope so late aborters can still see final values via MALL.
  if (everfast) {
    if (act) {
      __hip_atomic_store(pay0b + pW, lw0, __ATOMIC_RELAXED,
                         __HIP_MEMORY_SCOPE_AGENT);
      __hip_atomic_store(pay1b + pW, lw1, __ATOMIC_RELAXED,
                         __HIP_MEMORY_SCOPE_AGENT);
    }
    asm volatile("s_waitcnt vmcnt(0)" ::: "memory");
    if (lane == 0)
      __hip_atomic_store(flagw, lfv, __ATOMIC_RELAXED,
                         __HIP_MEMORY_SCOPE_AGENT);
  }

  if (act) {
    float* oc = out + (size_t)(g*GROWS + n)*H_DIM + u0 + quad*2;
    oc[0] = c0; oc[1] = c1;
    oc[HSZ + 0] = hf0; oc[HSZ + 1] = hf1;
  }
}

extern "C" void kernel_launch(void* const* d_in, const int* in_sizes, int n_in,
                              void* d_out, int out_size, void* d_ws, size_t ws_size,
                              hipStream_t stream) {
  const float* X    = (const float*)d_in[0];
  const float* Wx   = (const float*)d_in[1];
  const float* Wh   = (const float*)d_in[2];
  const float* bias = (const float*)d_in[3];
  float* out = (float*)d_out;

  char* ws = (char*)d_ws;
  h16* xp   = (h16*)ws;
  u64* hbuf = (u64*)(ws + XP_BYTES);
  h16* X16  = (h16*)(ws + XP_BYTES + HB_BYTES);
  h16* Wxp  = (h16*)(ws + XP_BYTES + HB_BYTES + X16_BYTES);

  // zero hbuf: payload zeros == h(0)=0; flags zero == step-0 ready
  hipMemsetAsync(ws + XP_BYTES, 0, HB_BYTES, stream);

  conv_x_kernel<<<4096, 256, 0, stream>>>(X, X16);
  conv_w_kernel<<<512, 256, 0, stream>>>(Wx, Wxp);
  xproj_kernel<<<8192, 256, 0, stream>>>(X16, Wxp, bias, xp);
  scan_kernel<<<NWG, 256, 0, stream>>>(Wh, xp, hbuf, out);
}

// Round 5
// 2320.256 us; speedup vs baseline: 1.0410x; 1.0410x over previous
//
#include <hip/hip_runtime.h>
#include <hip/hip_fp16.h>

#define T_DIM 1024
#define B_DIM 64
#define F_DIM 512
#define H_DIM 512
#define G4    2048
#define HSZ   (B_DIM*H_DIM)   // 32768

typedef _Float16 h16;
typedef unsigned long long u64;
typedef _Float16 v8h __attribute__((ext_vector_type(8)));
typedef _Float16 v4h __attribute__((ext_vector_type(4)));
typedef _Float16 v2h __attribute__((ext_vector_type(2)));
typedef float    v4f __attribute__((ext_vector_type(4)));
typedef unsigned v4u __attribute__((ext_vector_type(4)));
typedef unsigned v2u __attribute__((ext_vector_type(2)));

// scan decomposition: 8 row-groups x 8 rows, 16 WGs per group (grid 128).
// Teams formed by XCD census so each group's 16 WGs share one XCD ->
// h exchange via that XCD's L2 (plain store + nt load) instead of MALL.
// Protocol: r2 inline-tag (u64 = {tag, 2xfp16}) — detection IS data arrival;
// zero producer fence. (r4's split flag protocol measured +965cy/step from
// one extra L2 hop + store-ack fence; reverted.)
#define NGRP   8
#define GROWS  8
#define GWORDS 2048            // (8 rows * 512 units) / 2 fp16 per word
#define NWG    128
#define DESC_OFF  ((size_t)2*NGRP*GWORDS)     // census descriptors
#define TRIAL_OFF (DESC_OFF + NWG)            // visibility trial words
#define VOTE_OFF  (TRIAL_OFF + NWG)           // unanimity votes
#define ABORT_OFF (VOTE_OFF + NWG)            // per-group abort words

// workspace layout (bytes):
//   [0, 256MB)            xp: h16 [T][256 wg][2 tile][64 lane][4 reg]
//   [+0, +~260KB)         hbuf: u64 [2 phase][8 group][2048] + desc/trial/vote/abort
//   [.., +2MB)            Wxp: fp16 permuted Wx [2048 pc][512 k]
#define XP_HALVES ((size_t)T_DIM * 256 * 2 * 64 * 4)
#define XP_BYTES  (XP_HALVES * 2)
#define HB_WORDS  (ABORT_OFF + NGRP)
#define HB_BYTES  (HB_WORDS * 8)
#define WXP_BYTES ((size_t)G4 * F_DIM * 2)              // 2 MB

// ---------------------------------------------------------------------------
// Phase 0: Wx fp32 -> Wxp[pc][k] fp16, pre-permuted into staging order.
// (conv_x is gone: X fp32 is converted in-register inside xproj staging.)
// ---------------------------------------------------------------------------
__global__ __launch_bounds__(256) void conv_w_kernel(
    const float* __restrict__ Wx, h16* __restrict__ Wxp)
{
  const int gid = blockIdx.x * 256 + threadIdx.x;   // 512 blocks -> 131072
  const int pcg = gid >> 6;                         // 0..2047
  const int k8  = gid & 63;                         // 0..63 (8 k's each)
  const int ub  = pcg >> 5, Tt = (pcg >> 4) & 1, nn = pcg & 15;
  const int gcol = (Tt*2 + (nn >> 3))*512 + ub*8 + (nn & 7);
  v8h w;
  #pragma unroll
  for (int j = 0; j < 8; ++j)
    w[j] = (h16)Wx[(size_t)(k8*8 + j)*G4 + gcol];
  *(v8h*)(Wxp + (size_t)pcg*512 + k8*8) = w;
}

// ---------------------------------------------------------------------------
// Phase 1: x_proj = X @ Wxp + b -> fp16 MFMA C/D fragment layout.
// A-staging reads X fp32 and converts in-register (fused conv_x).
// ---------------------------------------------------------------------------
__global__ __launch_bounds__(256) void xproj_kernel(
    const float* __restrict__ X, const h16* __restrict__ Wxp,
    const float* __restrict__ bias, h16* __restrict__ xp)
{
  __shared__ __align__(16) h16 As[128*72];
  __shared__ __align__(16) h16 Bs[128*72];
  const int wgid = blockIdx.x;               // 8192 blocks
  const int wgn  = wgid & 15;
  const int bg   = (wgid >> 4) & 3;
  const int t0   = (wgid >> 6) * 8;
  const int tid  = threadIdx.x;
  const int lane = tid & 63;
  const int wv   = tid >> 6;
  const int mh   = wv & 1, nh = wv >> 1;
  const int n    = lane & 15, quad = lane >> 4;

  v4f acc[4][4];
  #pragma unroll
  for (int mi = 0; mi < 4; ++mi)
    #pragma unroll
    for (int ni = 0; ni < 4; ++ni) acc[mi][ni] = {0.f, 0.f, 0.f, 0.f};

  const int m  = tid >> 1;
  const int kh = tid & 1;
  const int abl = m & 15, atl = m >> 4;
  const float* asrc0 = X + ((size_t)(bg*16 + abl)*T_DIM + (t0 + atl))*F_DIM
                         + kh*32;
  const h16* bsrc0 = Wxp + (size_t)(wgn*128 + m)*512 + kh*32;
  h16* adst = As + m*72 + kh*32;
  h16* bdst = Bs + m*72 + kh*32;

  for (int kc = 0; kc < 8; ++kc) {
    __syncthreads();
    {
      const float* asrc = asrc0 + kc*64;
      const h16*   bsrc = bsrc0 + kc*64;
      #pragma unroll
      for (int j = 0; j < 32; j += 8) {
        float4 f0 = *(const float4*)(asrc + j);
        float4 f1 = *(const float4*)(asrc + j + 4);
        v8h wa = { (h16)f0.x, (h16)f0.y, (h16)f0.z, (h16)f0.w,
                   (h16)f1.x, (h16)f1.y, (h16)f1.z, (h16)f1.w };
        *(v8h*)(adst + j) = wa;
        *(v8h*)(bdst + j) = *(const v8h*)(bsrc + j);
      }
    }
    __syncthreads();
    #pragma unroll
    for (int kk = 0; kk < 2; ++kk) {
      v8h aF[4], bF[4];
      #pragma unroll
      for (int mi = 0; mi < 4; ++mi)
        aF[mi] = *(const v8h*)(As + ((mh*4 + mi)*16 + n)*72 + kk*32 + quad*8);
      #pragma unroll
      for (int ni = 0; ni < 4; ++ni)
        bF[ni] = *(const v8h*)(Bs + ((nh*4 + ni)*16 + n)*72 + kk*32 + quad*8);
      #pragma unroll
      for (int mi = 0; mi < 4; ++mi)
        #pragma unroll
        for (int ni = 0; ni < 4; ++ni)
          acc[mi][ni] = __builtin_amdgcn_mfma_f32_16x16x32_f16(
              aF[mi], bF[ni], acc[mi][ni], 0, 0, 0);
    }
  }
  #pragma unroll
  for (int ni = 0; ni < 4; ++ni) {
    int pc0  = wgn*128 + (nh*4 + ni)*16;
    int ub   = pc0 >> 5, Tt = (pc0 >> 4) & 1;
    int gcol = (Tt*2 + (n >> 3))*512 + ub*8 + (n & 7);
    float bv = bias[gcol];
    int wg2  = bg*64 + ub;
    #pragma unroll
    for (int mi = 0; mi < 4; ++mi) {
      int t = t0 + mh*4 + mi;
      size_t off = ((((size_t)t*256 + wg2)*2 + Tt)*256) + lane*4;
      v4h o = { (h16)(acc[mi][ni][0] + bv), (h16)(acc[mi][ni][1] + bv),
                (h16)(acc[mi][ni][2] + bv), (h16)(acc[mi][ni][3] + bv) };
      *(v4h*)(xp + off) = o;
    }
  }
}

// ---------------------------------------------------------------------------
// Phase 2: persistent scan with XCD-local exchange (nt poll + watchdog).
// ---------------------------------------------------------------------------
__device__ __forceinline__ float fsig(float x) {
  return __builtin_amdgcn_rcpf(1.f + __expf(-x));
}
__device__ __forceinline__ float ftanh(float x) {
  return 1.f - 2.f * __builtin_amdgcn_rcpf(__expf(2.f*x) + 1.f);
}

// nt load: no L1 allocation; served by XCD L2 when the line is there.
__device__ __forceinline__ u64 load_nt_u64(const u64* p) {
  v2u r;
  asm volatile("global_load_dwordx2 %0, %1, off nt\n\ts_waitcnt vmcnt(0)"
               : "=v"(r) : "v"(p) : "memory");
  return ((u64)r.y << 32) | (u64)r.x;
}

__global__ __launch_bounds__(256, 1) void scan_kernel(
    const float* __restrict__ Wh, const h16* __restrict__ xp,
    u64* __restrict__ hbuf, float* __restrict__ out)
{
  const int bx   = blockIdx.x;          // 0..127
  const int tid  = threadIdx.x;         // 0..255
  const int wv   = tid >> 6;
  const int lane = tid & 63;
  const int n    = lane & 15, quad = lane >> 4;

  __shared__ __align__(16) unsigned hlds[2][2052];  // 2048 payloads + zero pad
  __shared__ float gbuf[4][16*33];                  // per-wave gate exchange
  __shared__ unsigned char xcds[NWG];
  __shared__ unsigned char pos2bx[NWG];
  __shared__ int sflag[2];

  // ---- census: read physical XCD, publish, gather ----
  unsigned xcd;
  asm volatile("s_getreg_b32 %0, hwreg(20, 0, 32)" : "=s"(xcd)); // XCC_ID
  xcd &= 7u;
  u64* const desc = hbuf + DESC_OFF;
  if (tid == 0)
    __hip_atomic_store(desc + bx, ((u64)0xABu << 56) | (u64)xcd,
                       __ATOMIC_RELAXED, __HIP_MEMORY_SCOPE_AGENT);
  if (tid < NWG) {
    u64 d = __hip_atomic_load(desc + tid, __ATOMIC_RELAXED,
                              __HIP_MEMORY_SCOPE_AGENT);
    while ((unsigned)(d >> 56) != 0xABu) {
      __builtin_amdgcn_s_sleep(1);
      d = __hip_atomic_load(desc + tid, __ATOMIC_RELAXED,
                            __HIP_MEMORY_SCOPE_AGENT);
    }
    xcds[tid] = (unsigned char)(d & 7u);
  }
  if (tid < 4) { hlds[0][2048 + tid] = 0; hlds[1][2048 + tid] = 0; }
  __syncthreads();

  // deterministic team assignment: sort WGs by (xcd, bx); 16 consecutive
  // positions = one group. Fast iff the whole group sits in one xcd bucket.
  int start = 0, cnt = 0, rank = 0;
  for (int i = 0; i < NWG; ++i) {
    const int x = xcds[i];
    start += (x < (int)xcd) ? 1 : 0;
    cnt   += (x == (int)xcd) ? 1 : 0;
    rank  += (x == (int)xcd && i < bx) ? 1 : 0;
  }
  const int pos = start + rank;
  const int g = pos >> 4, w = pos & 15;     // group 0..7, slot 0..15
  bool fast = (g*16 >= start) && (g*16 + 16 <= start + cnt);

  // ---- trial handshake: plain-store -> nt-load visibility on this exact
  // placement; bounded wait, then agent-scope unanimous vote. ----
  if (fast) {
    if (tid < NWG) {
      const int xi = xcds[tid];
      int st = 0, rk = 0;
      for (int i = 0; i < NWG; ++i) {
        const int x = xcds[i];
        st += (x < xi) ? 1 : 0;
        rk += (x == xi && i < tid) ? 1 : 0;
      }
      pos2bx[st + rk] = (unsigned char)tid;
    }
    __syncthreads();
    u64* const trial = hbuf + TRIAL_OFF;
    u64* const vote  = hbuf + VOTE_OFF;
    if (tid == 0)
      __hip_atomic_store(trial + bx, ((u64)0xCDu << 56) | (u64)bx,
                         __ATOMIC_RELAXED, __HIP_MEMORY_SCOPE_WORKGROUP);
    int seen = 1;
    if (tid < 16) {
      const int tb = pos2bx[g*16 + tid];
      const u64 want = ((u64)0xCDu << 56) | (u64)tb;
      seen = 0;
      for (int it = 0; it < 1024; ++it) {
        if (load_nt_u64(trial + tb) == want) { seen = 1; break; }
        __builtin_amdgcn_s_sleep(1);
      }
    }
    if (tid < 64) {
      const int okw = __all(seen);
      if (tid == 0) sflag[0] = okw;
    }
    __syncthreads();
    if (tid == 0)
      __hip_atomic_store(vote + bx, ((u64)0xEFu << 56) | (u64)(sflag[0] & 1),
                         __ATOMIC_RELAXED, __HIP_MEMORY_SCOPE_AGENT);
    int vok = 1;
    if (tid < 16) {
      const int tb = pos2bx[g*16 + tid];
      u64 d = __hip_atomic_load(vote + tb, __ATOMIC_RELAXED,
                                __HIP_MEMORY_SCOPE_AGENT);
      while ((unsigned)(d >> 56) != 0xEFu) {
        __builtin_amdgcn_s_sleep(1);
        d = __hip_atomic_load(vote + tb, __ATOMIC_RELAXED,
                              __HIP_MEMORY_SCOPE_AGENT);
      }
      vok = (int)(d & 1);
    }
    if (tid < 64) {
      const int allv = __all(vok);
      if (tid == 0) sflag[1] = allv;
    }
    __syncthreads();
    fast = (sflag[1] != 0);
  }

  const int ub  = w*4 + wv;           // unit-block 0..63 (8 units)
  const int u0  = ub*8;
  const int g01 = n >> 3;
  const int uc  = u0 + (n & 7);

  // persistent B fragments: tile0 = gates {i,f}, tile1 = {g,o}
  v8h bF0[16], bF1[16];
  #pragma unroll
  for (int kk = 0; kk < 16; ++kk) {
    const int kb = kk*32 + quad*8;
    v8h f0, f1;
    #pragma unroll
    for (int j = 0; j < 8; ++j) {
      f0[j] = (h16)Wh[(size_t)(kb + j)*G4 + (g01*512 + uc)];
      f1[j] = (h16)Wh[(size_t)(kb + j)*G4 + ((2 + g01)*512 + uc)];
    }
    bF0[kk] = f0; bF1[kk] = f1;
  }

  float c0 = 0.f, c1 = 0.f, hf0 = 0.f, hf1 = 0.f;

  const bool act = (n < GROWS);              // h-owner lane (row n, 2 units)
  const int  pW  = ub*32 + n*4 + quad;       // producer word index
  u64* const gbase0 = hbuf + (size_t)g * GWORDS;
  u64* const gbase1 = hbuf + (size_t)(NGRP + g) * GWORDS;
  u64* const abw    = hbuf + ABORT_OFF + g;
  u64* const gb0p   = gbase0 + pW;           // deref gated by lw0 != 0
  u64* const gb1p   = gbase1 + pW;
  u64 lw0 = 0, lw1 = 0;                      // last plain-stored words (flush)

  // xp fragment remap: group g rows = old 16-row group (g>>1), quads (g&1)*2+{0,1}
  const int bgrp  = g >> 1;
  const int qq    = (g & 1)*2 + (quad & 1);
  const int lanep = n + 16*qq;
  size_t xoff = ((size_t)(bgrp*64 + ub)*2)*256 + lanep*4;
  v4h x0 = *(const v4h*)(xp + xoff);
  v4h x1 = *(const v4h*)(xp + xoff + 256);

  // A-fragment base in hlds (linear word layout); pad rows read the zero pad
  const int hbase = act ? (quad*32 + n*4) : 2048;
  const int hoff  = act ? 128 : 0;

  for (int t = 0; t < T_DIM; ++t) {
    const int p = t & 1;

    u64* const hb = (p ? gbase1 : gbase0) + tid*2;
    const unsigned target = (unsigned)t;
    unsigned pay0, pay1, pay2, pay3, pay4, pay5, pay6, pay7;
    bool got = false;

    if (fast) {
      const u64* a0 = hb;
      const u64* a1 = hb + 512;
      const u64* a2 = hb + 1024;
      const u64* a3 = hb + 1536;
      int rounds = 0;
      for (;;) {
        v4u q0, q1, q2, q3;
        asm volatile("global_load_dwordx4 %0, %1, off nt"
                     : "=v"(q0) : "v"(a0) : "memory");
        asm volatile("global_load_dwordx4 %0, %1, off nt"
                     : "=v"(q1) : "v"(a1) : "memory");
        asm volatile("global_load_dwordx4 %0, %1, off nt"
                     : "=v"(q2) : "v"(a2) : "memory");
        asm volatile("global_load_dwordx4 %0, %1, off nt"
                     : "=v"(q3) : "v"(a3) : "memory");
        asm volatile("s_waitcnt vmcnt(0)"
                     : "+v"(q0), "+v"(q1), "+v"(q2), "+v"(q3) :: "memory");
        __builtin_amdgcn_sched_barrier(0);
        const unsigned bad = (q0.y ^ target) | (q0.w ^ target)
                           | (q1.y ^ target) | (q1.w ^ target)
                           | (q2.y ^ target) | (q2.w ^ target)
                           | (q3.y ^ target) | (q3.w ^ target);
        if (__all((int)(bad == 0))) {
          pay0 = q0.x; pay1 = q0.z; pay2 = q1.x; pay3 = q1.z;
          pay4 = q2.x; pay5 = q2.z; pay6 = q3.x; pay7 = q3.z;
          got = true;
          break;
        }
        ++rounds;
        if ((rounds & 31) == 16) {
          // watchdog: abort word is agent-scope; on trip, flush the last
          // plain-stored words to MALL and fall back to the slow protocol.
          u64 ab = __hip_atomic_load(abw, __ATOMIC_RELAXED,
                                     __HIP_MEMORY_SCOPE_AGENT);
          if (__any((int)(ab != 0)) || rounds > 512) {
            __hip_atomic_store(abw, (u64)1, __ATOMIC_RELAXED,
                               __HIP_MEMORY_SCOPE_AGENT);
            if (lw0) __hip_atomic_store(gb0p, lw0, __ATOMIC_RELAXED,
                                        __HIP_MEMORY_SCOPE_AGENT);
            if (lw1) __hip_atomic_store(gb1p, lw1, __ATOMIC_RELAXED,
                                        __HIP_MEMORY_SCOPE_AGENT);
            fast = false;
            break;
          }
        }
        if (rounds > 6) __builtin_amdgcn_s_sleep(1);   // hot-spin first
      }
    }
    if (!got) {
      for (;;) {
        u64 wq[8];
        #pragma unroll
        for (int j = 0; j < 4; ++j) {
          wq[j*2]   = __hip_atomic_load(hb + j*512,     __ATOMIC_RELAXED,
                                        __HIP_MEMORY_SCOPE_AGENT);
          wq[j*2+1] = __hip_atomic_load(hb + j*512 + 1, __ATOMIC_RELAXED,
                                        __HIP_MEMORY_SCOPE_AGENT);
        }
        unsigned bad = 0;
        #pragma unroll
        for (int j = 0; j < 8; ++j)
          bad |= ((unsigned)(wq[j] >> 32)) ^ target;
        if (__all((int)(bad == 0))) {
          pay0 = (unsigned)wq[0]; pay1 = (unsigned)wq[1];
          pay2 = (unsigned)wq[2]; pay3 = (unsigned)wq[3];
          pay4 = (unsigned)wq[4]; pay5 = (unsigned)wq[5];
          pay6 = (unsigned)wq[6]; pay7 = (unsigned)wq[7];
          break;
        }
        __builtin_amdgcn_s_sleep(1);
      }
    }

    // xp prefetch for t+1: issued HERE (right after the poll) so its ~900cy
    // HBM latency hides under this step's compute + the NEXT step's poll
    // rounds. In-order vmcnt retirement means anything issued later than the
    // poll loads would otherwise expose its residual latency in the poll's
    // vmcnt(0).
    v4h nx0 = x0, nx1 = x1;
    if (t + 1 < T_DIM) {
      const size_t nxo = (((size_t)(t+1)*256 + bgrp*64 + ub)*2)*256 + lanep*4;
      nx0 = *(const v4h*)(xp + nxo);
      nx1 = *(const v4h*)(xp + nxo + 256);
    }

    // redistribute payload dwords into linear hlds (b64 writes, 2-way free)
    {
      v2u* hl = (v2u*)hlds[p];
      hl[tid]       = (v2u){pay0, pay1};
      hl[tid + 256] = (v2u){pay2, pay3};
      hl[tid + 512] = (v2u){pay4, pay5};
      hl[tid + 768] = (v2u){pay6, pay7};
    }
    __syncthreads();

    v4f acc0 = { (float)x0[0], (float)x0[1], (float)x0[2], (float)x0[3] };
    v4f acc1 = { (float)x1[0], (float)x1[1], (float)x1[2], (float)x1[3] };
    v4f acc2 = { 0.f, 0.f, 0.f, 0.f };
    v4f acc3 = { 0.f, 0.f, 0.f, 0.f };
    const unsigned* hfr = &hlds[p][hbase];
    #pragma unroll
    for (int kk = 0; kk < 8; ++kk) {
      v8h a0 = *(const v8h*)(hfr + kk*hoff);
      v8h a1 = *(const v8h*)(hfr + (kk+8)*hoff);
      acc0 = __builtin_amdgcn_mfma_f32_16x16x32_f16(a0, bF0[kk],   acc0, 0,0,0);
      acc1 = __builtin_amdgcn_mfma_f32_16x16x32_f16(a0, bF1[kk],   acc1, 0,0,0);
      acc2 = __builtin_amdgcn_mfma_f32_16x16x32_f16(a1, bF0[kk+8], acc2, 0,0,0);
      acc3 = __builtin_amdgcn_mfma_f32_16x16x32_f16(a1, bF1[kk+8], acc3, 0,0,0);
    }
    acc0 += acc2; acc1 += acc3;

    // gate exchange within wave (rows 0..7 valid; pad rows written, unused)
    float* gb = gbuf[wv];
    #pragma unroll
    for (int r = 0; r < 4; ++r) {
      const int row = quad*4 + r;
      gb[row*33 + n]      = acc0[r];
      gb[row*33 + 16 + n] = acc1[r];
    }
    __builtin_amdgcn_wave_barrier();
    const float* gr = gb + n*33;
    const int ua2 = quad*2;
    float gi0 = gr[ua2],   gf0 = gr[8+ua2], gg0 = gr[16+ua2], go0 = gr[24+ua2];
    float gi1 = gr[ua2+1], gf1 = gr[9+ua2], gg1 = gr[17+ua2], go1 = gr[25+ua2];
    __builtin_amdgcn_wave_barrier();

    gi0 = fsig(gi0); gf0 = fsig(gf0); gg0 = ftanh(gg0); go0 = fsig(go0);
    gi1 = fsig(gi1); gf1 = fsig(gf1); gg1 = ftanh(gg1); go1 = fsig(go1);
    c0 = gf0*c0 + gi0*gg0;  hf0 = go0*ftanh(c0);
    c1 = gf1*c1 + gi1*gg1;  hf1 = go1*ftanh(c1);

    // tagged h store: fast = plain (write-back into the shared XCD L2);
    // slow = agent-scope (write-through to MALL)
    if (t < T_DIM - 1 && act) {
      union { v2h v; unsigned u; } pw;
      pw.v = (v2h){ (h16)hf0, (h16)hf1 };
      const u64 word = ((u64)(unsigned)(t + 1) << 32) | (u64)pw.u;
      u64* const hwp = (p ? gbase0 : gbase1) + pW;
      if (fast) {
        __hip_atomic_store(hwp, word, __ATOMIC_RELAXED,
                           __HIP_MEMORY_SCOPE_WORKGROUP);
        if (p) lw0 = word; else lw1 = word;
      } else {
        __hip_atomic_store(hwp, word, __ATOMIC_RELAXED,
                           __HIP_MEMORY_SCOPE_AGENT);
      }
    }
    x0 = nx0; x1 = nx1;
  }

  if (act) {
    float* oc = out + (size_t)(g*GROWS + n)*H_DIM + u0 + quad*2;
    oc[0] = c0; oc[1] = c1;
    oc[HSZ + 0] = hf0; oc[HSZ + 1] = hf1;
  }
}

extern "C" void kernel_launch(void* const* d_in, const int* in_sizes, int n_in,
                              void* d_out, int out_size, void* d_ws, size_t ws_size,
                              hipStream_t stream) {
  const float* X    = (const float*)d_in[0];
  const float* Wx   = (const float*)d_in[1];
  const float* Wh   = (const float*)d_in[2];
  const float* bias = (const float*)d_in[3];
  float* out = (float*)d_out;

  char* ws = (char*)d_ws;
  h16* xp   = (h16*)ws;
  u64* hbuf = (u64*)(ws + XP_BYTES);
  h16* Wxp  = (h16*)(ws + XP_BYTES + HB_BYTES);

  // zero hbuf + census/trial/vote/abort words (tags -> 0 == t=0 target)
  hipMemsetAsync(ws + XP_BYTES, 0, HB_BYTES, stream);

  conv_w_kernel<<<512, 256, 0, stream>>>(Wx, Wxp);
  xproj_kernel<<<8192, 256, 0, stream>>>(X, Wxp, bias, xp);
  scan_kernel<<<NWG, 256, 0, stream>>>(Wh, xp, hbuf, out);
}

// Round 6
// 1794.373 us; speedup vs baseline: 1.3461x; 1.2931x over previous
//
#include <hip/hip_runtime.h>
#include <hip/hip_fp16.h>

#define T_DIM 1024
#define B_DIM 64
#define F_DIM 512
#define H_DIM 512
#define G4    2048
#define HSZ   (B_DIM*H_DIM)   // 32768

typedef _Float16 h16;
typedef unsigned long long u64;
typedef _Float16 v8h __attribute__((ext_vector_type(8)));
typedef _Float16 v4h __attribute__((ext_vector_type(4)));
typedef _Float16 v2h __attribute__((ext_vector_type(2)));
typedef float    v4f __attribute__((ext_vector_type(4)));
typedef unsigned v4u __attribute__((ext_vector_type(4)));
typedef unsigned v2u __attribute__((ext_vector_type(2)));

// scan decomposition: 8 row-groups x 8 rows, 16 WGs per group (grid 128).
// Teams formed by XCD census; h exchange via that XCD's L2 (plain store +
// nt load). Protocol: r2 inline-tag (u64 = {tag, 2xfp16}).
// NEW (r6): swapped-operand MFMA (A = Wh^T fragments, B = h fragments) with
// gate-interleaved M-tile packing (row = u_local*4 + gate, units even/odd
// across tile pair) -> each lane's acc IS {i,f,g,o} for its 2 adjacent
// units x its batch row. The LDS gate exchange + 2 wave_barriers are gone.
#define NGRP   8
#define GROWS  8
#define GWORDS 2048            // (8 rows * 512 units) / 2 fp16 per word
#define NWG    128
#define DESC_OFF  ((size_t)2*NGRP*GWORDS)     // census descriptors
#define TRIAL_OFF (DESC_OFF + NWG)            // visibility trial words
#define VOTE_OFF  (TRIAL_OFF + NWG)           // unanimity votes
#define ABORT_OFF (VOTE_OFF + NWG)            // per-group abort words

// workspace layout (bytes):
//   [0, 256MB)    xp: h16 [T][4 bblk][128 Mtile][64 lane][4 gate-reg]
//   [+0, +260KB)  hbuf: u64 [2 phase][8 group][2048] + desc/trial/vote/abort
//   [.., +64MB)   X16: fp16 copy of X [B][T][F]
//   [.., +2MB)    Wxp: fp16 permuted Wx [2048 pc][512 k]
#define XP_HALVES ((size_t)T_DIM * 512 * 64 * 4)
#define XP_BYTES  (XP_HALVES * 2)
#define HB_WORDS  (ABORT_OFF + NGRP)
#define HB_BYTES  (HB_WORDS * 8)
#define X16_BYTES ((size_t)B_DIM * T_DIM * F_DIM * 2)   // 64 MB
#define WXP_BYTES ((size_t)G4 * F_DIM * 2)              // 2 MB

// ---------------------------------------------------------------------------
// Phase 0a: X fp32 -> fp16, straight copy (bandwidth-bound).
// ---------------------------------------------------------------------------
__global__ __launch_bounds__(256) void conv_x_kernel(
    const float* __restrict__ X, h16* __restrict__ X16)
{
  const size_t total4 = (size_t)B_DIM * T_DIM * F_DIM / 4;   // 8388608
  for (size_t i = blockIdx.x * 256 + threadIdx.x; i < total4;
       i += (size_t)gridDim.x * 256) {
    float4 v = ((const float4*)X)[i];
    v4h w = { (h16)v.x, (h16)v.y, (h16)v.z, (h16)v.w };
    ((v4h*)X16)[i] = w;
  }
}

// ---------------------------------------------------------------------------
// Phase 0b: Wx fp32 -> Wxp[pc][k] fp16 (A-operand rows, gate-interleaved).
// pc = Mtile*16 + (u_local*4 + gate); Mtile = ub*2 + par;
// gcol = gate*512 + ub*8 + 2*u_local + par.
// ---------------------------------------------------------------------------
__global__ __launch_bounds__(256) void conv_w_kernel(
    const float* __restrict__ Wx, h16* __restrict__ Wxp)
{
  const int gid = blockIdx.x * 256 + threadIdx.x;   // 512 blocks -> 131072
  const int pcg = gid >> 6;                         // 0..2047
  const int k8  = gid & 63;                         // 0..63 (8 k's each)
  const int Mt  = pcg >> 4, mrow = pcg & 15;
  const int ub  = Mt >> 1, par = Mt & 1;
  const int ul  = mrow >> 2, gate = mrow & 3;
  const int gcol = gate*512 + ub*8 + 2*ul + par;
  v8h w;
  #pragma unroll
  for (int j = 0; j < 8; ++j)
    w[j] = (h16)Wx[(size_t)(k8*8 + j)*G4 + gcol];
  *(v8h*)(Wxp + (size_t)pcg*512 + k8*8) = w;
}

// ---------------------------------------------------------------------------
// Phase 1: x_proj^T tiles = Wxp (A) x X16 (B) + bias(row).
// D: col = batch row (n), row = u_local*4 + gate -> matches scan fragments.
// ---------------------------------------------------------------------------
__global__ __launch_bounds__(256) void xproj_kernel(
    const h16* __restrict__ X16, const h16* __restrict__ Wxp,
    const float* __restrict__ bias, h16* __restrict__ xp)
{
  __shared__ __align__(16) h16 As[128*72];   // [pc-local 0..127][k 0..63]
  __shared__ __align__(16) h16 Bs[128*72];   // [t_loc*16+batch][k 0..63]
  const int wgid = blockIdx.x;               // 8192 blocks
  const int wgn  = wgid & 15;                // M block (128 gate-cols)
  const int bg   = (wgid >> 4) & 3;          // batch group (16 rows)
  const int t0   = (wgid >> 6) * 8;          // 8 consecutive t per WG
  const int tid  = threadIdx.x;
  const int lane = tid & 63;
  const int wv   = tid >> 6;
  const int mh   = wv & 1, nh = wv >> 1;
  const int n    = lane & 15, quad = lane >> 4;

  v4f acc[4][4];
  #pragma unroll
  for (int mi = 0; mi < 4; ++mi)
    #pragma unroll
    for (int ni = 0; ni < 4; ++ni) acc[mi][ni] = {0.f, 0.f, 0.f, 0.f};

  const int m  = tid >> 1;        // row 0..127 (A: pc-local, B: t*16+batch)
  const int kh = tid & 1;         // k half (32 fp16 = 64 B)
  const int bbl = m & 15, btl = m >> 4;
  const h16* asrc0 = Wxp + (size_t)(wgn*128 + m)*512 + kh*32;
  const h16* bsrc0 = X16 + ((size_t)(bg*16 + bbl)*T_DIM + (t0 + btl))*F_DIM
                         + kh*32;
  h16* adst = As + m*72 + kh*32;
  h16* bdst = Bs + m*72 + kh*32;

  for (int kc = 0; kc < 8; ++kc) {
    __syncthreads();
    {
      const h16* asrc = asrc0 + kc*64;
      const h16* bsrc = bsrc0 + kc*64;
      #pragma unroll
      for (int j = 0; j < 32; j += 8) {
        *(v8h*)(adst + j) = *(const v8h*)(asrc + j);
        *(v8h*)(bdst + j) = *(const v8h*)(bsrc + j);
      }
    }
    __syncthreads();
    #pragma unroll
    for (int kk = 0; kk < 2; ++kk) {
      v8h aF[4], bF[4];
      #pragma unroll
      for (int mi = 0; mi < 4; ++mi)
        aF[mi] = *(const v8h*)(As + ((mh*4 + mi)*16 + n)*72 + kk*32 + quad*8);
      #pragma unroll
      for (int ni = 0; ni < 4; ++ni)
        bF[ni] = *(const v8h*)(Bs + ((nh*4 + ni)*16 + n)*72 + kk*32 + quad*8);
      #pragma unroll
      for (int mi = 0; mi < 4; ++mi)
        #pragma unroll
        for (int ni = 0; ni < 4; ++ni)
          acc[mi][ni] = __builtin_amdgcn_mfma_f32_16x16x32_f16(
              aF[mi], bF[ni], acc[mi][ni], 0, 0, 0);
    }
  }
  // epilogue: D row (quad*4+r) = u_local(quad)*4 + gate(r); bias per row
  #pragma unroll
  for (int mi = 0; mi < 4; ++mi) {
    const int Mg  = wgn*8 + mh*4 + mi;       // global M-tile 0..127
    const int ub  = Mg >> 1, par = Mg & 1;
    const int unit = ub*8 + 2*quad + par;
    v4f bv = { bias[unit], bias[512 + unit],
               bias[1024 + unit], bias[1536 + unit] };
    #pragma unroll
    for (int ni = 0; ni < 4; ++ni) {
      const int t = t0 + nh*4 + ni;
      size_t off = (((size_t)t*512 + bg*128 + Mg)*64 + quad*16 + n)*4;
      v4h o = { (h16)(acc[mi][ni][0] + bv[0]), (h16)(acc[mi][ni][1] + bv[1]),
                (h16)(acc[mi][ni][2] + bv[2]), (h16)(acc[mi][ni][3] + bv[3]) };
      *(v4h*)(xp + off) = o;
    }
  }
}

// ---------------------------------------------------------------------------
// Phase 2: persistent scan with XCD-local exchange (nt poll + watchdog).
// ---------------------------------------------------------------------------
__device__ __forceinline__ float fsig(float x) {
  return __builtin_amdgcn_rcpf(1.f + __expf(-x));
}
__device__ __forceinline__ float ftanh(float x) {
  return 1.f - 2.f * __builtin_amdgcn_rcpf(__expf(2.f*x) + 1.f);
}

// nt load: no L1 allocation; served by XCD L2 when the line is there.
__device__ __forceinline__ u64 load_nt_u64(const u64* p) {
  v2u r;
  asm volatile("global_load_dwordx2 %0, %1, off nt\n\ts_waitcnt vmcnt(0)"
               : "=v"(r) : "v"(p) : "memory");
  return ((u64)r.y << 32) | (u64)r.x;
}

__global__ __launch_bounds__(256, 1) void scan_kernel(
    const float* __restrict__ Wh, const h16* __restrict__ xp,
    u64* __restrict__ hbuf, float* __restrict__ out)
{
  const int bx   = blockIdx.x;          // 0..127
  const int tid  = threadIdx.x;         // 0..255
  const int wv   = tid >> 6;
  const int lane = tid & 63;
  const int n    = lane & 15, quad = lane >> 4;

  __shared__ __align__(16) unsigned hlds[2][2052];  // 2048 payloads + zero pad
  __shared__ unsigned char xcds[NWG];
  __shared__ unsigned char pos2bx[NWG];
  __shared__ int sflag[2];

  // ---- census: read physical XCD, publish, gather ----
  unsigned xcd;
  asm volatile("s_getreg_b32 %0, hwreg(20, 0, 32)" : "=s"(xcd)); // XCC_ID
  xcd &= 7u;
  u64* const desc = hbuf + DESC_OFF;
  if (tid == 0)
    __hip_atomic_store(desc + bx, ((u64)0xABu << 56) | (u64)xcd,
                       __ATOMIC_RELAXED, __HIP_MEMORY_SCOPE_AGENT);
  if (tid < NWG) {
    u64 d = __hip_atomic_load(desc + tid, __ATOMIC_RELAXED,
                              __HIP_MEMORY_SCOPE_AGENT);
    while ((unsigned)(d >> 56) != 0xABu) {
      __builtin_amdgcn_s_sleep(1);
      d = __hip_atomic_load(desc + tid, __ATOMIC_RELAXED,
                            __HIP_MEMORY_SCOPE_AGENT);
    }
    xcds[tid] = (unsigned char)(d & 7u);
  }
  if (tid < 4) { hlds[0][2048 + tid] = 0; hlds[1][2048 + tid] = 0; }
  __syncthreads();

  // deterministic team assignment: sort WGs by (xcd, bx)
  int start = 0, cnt = 0, rank = 0;
  for (int i = 0; i < NWG; ++i) {
    const int x = xcds[i];
    start += (x < (int)xcd) ? 1 : 0;
    cnt   += (x == (int)xcd) ? 1 : 0;
    rank  += (x == (int)xcd && i < bx) ? 1 : 0;
  }
  const int pos = start + rank;
  const int g = pos >> 4, w = pos & 15;     // group 0..7, slot 0..15
  bool fast = (g*16 >= start) && (g*16 + 16 <= start + cnt);

  // ---- trial handshake (plain-store -> nt-load), agent-scope vote ----
  if (fast) {
    if (tid < NWG) {
      const int xi = xcds[tid];
      int st = 0, rk = 0;
      for (int i = 0; i < NWG; ++i) {
        const int x = xcds[i];
        st += (x < xi) ? 1 : 0;
        rk += (x == xi && i < tid) ? 1 : 0;
      }
      pos2bx[st + rk] = (unsigned char)tid;
    }
    __syncthreads();
    u64* const trial = hbuf + TRIAL_OFF;
    u64* const vote  = hbuf + VOTE_OFF;
    if (tid == 0)
      __hip_atomic_store(trial + bx, ((u64)0xCDu << 56) | (u64)bx,
                         __ATOMIC_RELAXED, __HIP_MEMORY_SCOPE_WORKGROUP);
    int seen = 1;
    if (tid < 16) {
      const int tb = pos2bx[g*16 + tid];
      const u64 want = ((u64)0xCDu << 56) | (u64)tb;
      seen = 0;
      for (int it = 0; it < 1024; ++it) {
        if (load_nt_u64(trial + tb) == want) { seen = 1; break; }
        __builtin_amdgcn_s_sleep(1);
      }
    }
    if (tid < 64) {
      const int okw = __all(seen);
      if (tid == 0) sflag[0] = okw;
    }
    __syncthreads();
    if (tid == 0)
      __hip_atomic_store(vote + bx, ((u64)0xEFu << 56) | (u64)(sflag[0] & 1),
                         __ATOMIC_RELAXED, __HIP_MEMORY_SCOPE_AGENT);
    int vok = 1;
    if (tid < 16) {
      const int tb = pos2bx[g*16 + tid];
      u64 d = __hip_atomic_load(vote + tb, __ATOMIC_RELAXED,
                                __HIP_MEMORY_SCOPE_AGENT);
      while ((unsigned)(d >> 56) != 0xEFu) {
        __builtin_amdgcn_s_sleep(1);
        d = __hip_atomic_load(vote + tb, __ATOMIC_RELAXED,
                              __HIP_MEMORY_SCOPE_AGENT);
      }
      vok = (int)(d & 1);
    }
    if (tid < 64) {
      const int allv = __all(vok);
      if (tid == 0) sflag[1] = allv;
    }
    __syncthreads();
    fast = (sflag[1] != 0);
  }

  const int ub = w*4 + wv;            // unit-block 0..63 (8 units)
  const int u0 = ub*8;

  // persistent A fragments (Wh^T, gate-interleaved M-rows):
  // lane M-row n = u_local*4 + gate; whF0 = even units, whF1 = odd.
  v8h whF0[16], whF1[16];
  {
    const int gate = n & 3, ul = n >> 2;
    const int ce = gate*512 + u0 + 2*ul;     // even-unit column
    #pragma unroll
    for (int kk = 0; kk < 16; ++kk) {
      const int kb = kk*32 + quad*8;
      v8h f0, f1;
      #pragma unroll
      for (int j = 0; j < 8; ++j) {
        f0[j] = (h16)Wh[(size_t)(kb + j)*G4 + ce];
        f1[j] = (h16)Wh[(size_t)(kb + j)*G4 + ce + 1];
      }
      whF0[kk] = f0; whF1[kk] = f1;
    }
  }

  float c0 = 0.f, c1 = 0.f, hf0 = 0.f, hf1 = 0.f;

  const bool act = (n < GROWS);              // batch-row owner lane
  const int  pW  = w*128 + wv*32 + n*4 + quad;   // producer word index
  u64* const gbase0 = hbuf + (size_t)g * GWORDS;
  u64* const gbase1 = hbuf + (size_t)(NGRP + g) * GWORDS;
  u64* const abw    = hbuf + ABORT_OFF + g;
  u64* const gb0p   = gbase0 + pW;
  u64* const gb1p   = gbase1 + pW;
  u64 lw0 = 0, lw1 = 0;

  // xp fragment address: [t][bgrp*128 + ub*2 + tile][quad*16 + ghalf + n][4]
  const int bgrp  = g >> 1;
  const int ghalf = (g & 1)*8;
  const int lpos  = quad*16 + ghalf + n;
  size_t xoff = (((size_t)bgrp*128 + ub*2)*64 + lpos)*4;
  v4h x0 = *(const v4h*)(xp + xoff);         // tile even units
  v4h x1 = *(const v4h*)(xp + xoff + 256);   // tile odd units

  // B-fragment base in hlds; pad rows (n>=8) read the zero pad
  const int hbase = act ? (quad*32 + n*4) : 2048;
  const int hoff  = act ? 128 : 0;

  for (int t = 0; t < T_DIM; ++t) {
    const int p = t & 1;

    u64* const hb = (p ? gbase1 : gbase0) + tid*2;
    const unsigned target = (unsigned)t;
    unsigned pay0, pay1, pay2, pay3, pay4, pay5, pay6, pay7;
    bool got = false;

    if (fast) {
      const u64* a0 = hb;
      const u64* a1 = hb + 512;
      const u64* a2 = hb + 1024;
      const u64* a3 = hb + 1536;
      int rounds = 0;
      for (;;) {
        v4u q0, q1, q2, q3;
        asm volatile("global_load_dwordx4 %0, %1, off nt"
                     : "=v"(q0) : "v"(a0) : "memory");
        asm volatile("global_load_dwordx4 %0, %1, off nt"
                     : "=v"(q1) : "v"(a1) : "memory");
        asm volatile("global_load_dwordx4 %0, %1, off nt"
                     : "=v"(q2) : "v"(a2) : "memory");
        asm volatile("global_load_dwordx4 %0, %1, off nt"
                     : "=v"(q3) : "v"(a3) : "memory");
        asm volatile("s_waitcnt vmcnt(0)"
                     : "+v"(q0), "+v"(q1), "+v"(q2), "+v"(q3) :: "memory");
        __builtin_amdgcn_sched_barrier(0);
        const unsigned bad = (q0.y ^ target) | (q0.w ^ target)
                           | (q1.y ^ target) | (q1.w ^ target)
                           | (q2.y ^ target) | (q2.w ^ target)
                           | (q3.y ^ target) | (q3.w ^ target);
        if (__all((int)(bad == 0))) {
          pay0 = q0.x; pay1 = q0.z; pay2 = q1.x; pay3 = q1.z;
          pay4 = q2.x; pay5 = q2.z; pay6 = q3.x; pay7 = q3.z;
          got = true;
          break;
        }
        ++rounds;
        if ((rounds & 31) == 16) {
          u64 ab = __hip_atomic_load(abw, __ATOMIC_RELAXED,
                                     __HIP_MEMORY_SCOPE_AGENT);
          if (__any((int)(ab != 0)) || rounds > 512) {
            __hip_atomic_store(abw, (u64)1, __ATOMIC_RELAXED,
                               __HIP_MEMORY_SCOPE_AGENT);
            if (lw0) __hip_atomic_store(gb0p, lw0, __ATOMIC_RELAXED,
                                        __HIP_MEMORY_SCOPE_AGENT);
            if (lw1) __hip_atomic_store(gb1p, lw1, __ATOMIC_RELAXED,
                                        __HIP_MEMORY_SCOPE_AGENT);
            fast = false;
            break;
          }
        }
        if (rounds > 6) __builtin_amdgcn_s_sleep(1);   // hot-spin first
      }
    }
    if (!got) {
      for (;;) {
        u64 wq[8];
        #pragma unroll
        for (int j = 0; j < 4; ++j) {
          wq[j*2]   = __hip_atomic_load(hb + j*512,     __ATOMIC_RELAXED,
                                        __HIP_MEMORY_SCOPE_AGENT);
          wq[j*2+1] = __hip_atomic_load(hb + j*512 + 1, __ATOMIC_RELAXED,
                                        __HIP_MEMORY_SCOPE_AGENT);
        }
        unsigned bad = 0;
        #pragma unroll
        for (int j = 0; j < 8; ++j)
          bad |= ((unsigned)(wq[j] >> 32)) ^ target;
        if (__all((int)(bad == 0))) {
          pay0 = (unsigned)wq[0]; pay1 = (unsigned)wq[1];
          pay2 = (unsigned)wq[2]; pay3 = (unsigned)wq[3];
          pay4 = (unsigned)wq[4]; pay5 = (unsigned)wq[5];
          pay6 = (unsigned)wq[6]; pay7 = (unsigned)wq[7];
          break;
        }
        __builtin_amdgcn_s_sleep(1);
      }
    }

    // redistribute payload dwords into linear hlds (identity map)
    {
      v2u* hl = (v2u*)hlds[p];
      hl[tid]       = (v2u){pay0, pay1};
      hl[tid + 256] = (v2u){pay2, pay3};
      hl[tid + 512] = (v2u){pay4, pay5};
      hl[tid + 768] = (v2u){pay6, pay7};
    }
    __syncthreads();

    // xp prefetch for t+1: post-barrier (r2 position) — its HBM latency
    // hides under this step's MFMA/VALU + the next step's poll rounds.
    v4h nx0 = x0, nx1 = x1;
    if (t + 1 < T_DIM) {
      const size_t nxo = (((size_t)(t+1)*512 + bgrp*128 + ub*2)*64 + lpos)*4;
      nx0 = *(const v4h*)(xp + nxo);
      nx1 = *(const v4h*)(xp + nxo + 256);
    }

    v4f acc0 = { (float)x0[0], (float)x0[1], (float)x0[2], (float)x0[3] };
    v4f acc1 = { (float)x1[0], (float)x1[1], (float)x1[2], (float)x1[3] };
    v4f acc2 = { 0.f, 0.f, 0.f, 0.f };
    v4f acc3 = { 0.f, 0.f, 0.f, 0.f };
    const unsigned* hfr = &hlds[p][hbase];
    #pragma unroll
    for (int kk = 0; kk < 8; ++kk) {
      v8h b0 = *(const v8h*)(hfr + kk*hoff);
      v8h b1 = *(const v8h*)(hfr + (kk+8)*hoff);
      acc0 = __builtin_amdgcn_mfma_f32_16x16x32_f16(whF0[kk],   b0, acc0, 0,0,0);
      acc1 = __builtin_amdgcn_mfma_f32_16x16x32_f16(whF1[kk],   b0, acc1, 0,0,0);
      acc2 = __builtin_amdgcn_mfma_f32_16x16x32_f16(whF0[kk+8], b1, acc2, 0,0,0);
      acc3 = __builtin_amdgcn_mfma_f32_16x16x32_f16(whF1[kk+8], b1, acc3, 0,0,0);
    }
    acc0 += acc2; acc1 += acc3;

    // gates directly from acc: acc0 = {i,f,g,o} unit u0+2q; acc1 = unit +1
    float gi0 = fsig(acc0[0]),  gf0 = fsig(acc0[1]);
    float gg0 = ftanh(acc0[2]), go0 = fsig(acc0[3]);
    float gi1 = fsig(acc1[0]),  gf1 = fsig(acc1[1]);
    float gg1 = ftanh(acc1[2]), go1 = fsig(acc1[3]);
    c0 = gf0*c0 + gi0*gg0;  hf0 = go0*ftanh(c0);
    c1 = gf1*c1 + gi1*gg1;  hf1 = go1*ftanh(c1);

    // tagged h store: {hi: t+1, lo: h[even unit], h[odd unit]}
    if (t < T_DIM - 1 && act) {
      union { v2h v; unsigned u; } pw;
      pw.v = (v2h){ (h16)hf0, (h16)hf1 };
      const u64 word = ((u64)(unsigned)(t + 1) << 32) | (u64)pw.u;
      u64* const hwp = (p ? gbase0 : gbase1) + pW;
      if (fast) {
        __hip_atomic_store(hwp, word, __ATOMIC_RELAXED,
                           __HIP_MEMORY_SCOPE_WORKGROUP);
        if (p) lw0 = word; else lw1 = word;
      } else {
        __hip_atomic_store(hwp, word, __ATOMIC_RELAXED,
                           __HIP_MEMORY_SCOPE_AGENT);
      }
    }
    x0 = nx0; x1 = nx1;
  }

  if (act) {
    float* oc = out + (size_t)(g*GROWS + n)*H_DIM + u0 + quad*2;
    oc[0] = c0; oc[1] = c1;
    oc[HSZ + 0] = hf0; oc[HSZ + 1] = hf1;
  }
}

extern "C" void kernel_launch(void* const* d_in, const int* in_sizes, int n_in,
                              void* d_out, int out_size, void* d_ws, size_t ws_size,
                              hipStream_t stream) {
  const float* X    = (const float*)d_in[0];
  const float* Wx   = (const float*)d_in[1];
  const float* Wh   = (const float*)d_in[2];
  const float* bias = (const float*)d_in[3];
  float* out = (float*)d_out;

  char* ws = (char*)d_ws;
  h16* xp   = (h16*)ws;
  u64* hbuf = (u64*)(ws + XP_BYTES);
  h16* X16  = (h16*)(ws + XP_BYTES + HB_BYTES);
  h16* Wxp  = (h16*)(ws + XP_BYTES + HB_BYTES + X16_BYTES);

  // zero hbuf + census/trial/vote/abort words (tags -> 0 == t=0 target)
  hipMemsetAsync(ws + XP_BYTES, 0, HB_BYTES, stream);

  conv_x_kernel<<<4096, 256, 0, stream>>>(X, X16);
  conv_w_kernel<<<512, 256, 0, stream>>>(Wx, Wxp);
  xproj_kernel<<<8192, 256, 0, stream>>>(X16, Wxp, bias, xp);
  scan_kernel<<<NWG, 256, 0, stream>>>(Wh, xp, hbuf, out);
}